// Round 11
// baseline (120.302 us; speedup 1.0000x reference)
//
#include <hip/hip_runtime.h>
#include <hip/hip_bf16.h>

// HGNN forward, MI355X.
// R11 = R9 (best, 116.1us) + two structural moves:
//  (1) dsd branch moved into the k_cvt launch (k_pre): dsd reads only fp32
//      E_s/E_d, independent of Ebf; latency-bound dsd overlaps BW-bound cvt.
//      dsd blocks first (0-255) so gather chains start immediately.
//  (2) final W1u stage as bf16 MFMA (R10-measured: absmax unchanged),
//      replacing fp32 W1u staging + serial wave-0 readlane-dot.
// R10's wave-autonomous stage-1 REVERTED (cost 3.6us: 2x MFMA duplication).

typedef __attribute__((ext_vector_type(8))) short short8;
typedef __attribute__((ext_vector_type(8))) unsigned short ushort8;
typedef __attribute__((ext_vector_type(4))) float f32x4;

__device__ __forceinline__ int rfl(int v) { return __builtin_amdgcn_readfirstlane(v); }
__device__ __forceinline__ float leakyf(float x) { return x >= 0.f ? x : 0.2f * x; }

__device__ __forceinline__ unsigned short bf16bits(float x) {
    __hip_bfloat16 h = __float2bfloat16(x);
    return __builtin_bit_cast(unsigned short, h);
}
__device__ __forceinline__ float bflo(unsigned int u) { return __uint_as_float(u << 16); }
__device__ __forceinline__ float bfhi(unsigned int u) { return __uint_as_float(u & 0xffff0000u); }

#define XP 72   // bf16 matrix row pitch in shorts (144 B: 16B-aligned)

// 4-MFMA pair-matmul accumulate: acc = As@Wb1(K64) + Am@Wb2(K64)
__device__ __forceinline__ f32x4 pair_mfma(
    const unsigned short* sXs, const unsigned short* sXm,
    const unsigned short* sWb1, const unsigned short* sWb2,
    int arow, int brow, int quad)
{
    const int ab = arow * XP + quad * 8;
    const int bb = brow * XP + quad * 8;
    short8 as0 = *(const short8*)(sXs + ab);
    short8 as1 = *(const short8*)(sXs + ab + 32);
    short8 am0 = *(const short8*)(sXm + ab);
    short8 am1 = *(const short8*)(sXm + ab + 32);
    short8 b10 = *(const short8*)(sWb1 + bb);
    short8 b11 = *(const short8*)(sWb1 + bb + 32);
    short8 b20 = *(const short8*)(sWb2 + bb);
    short8 b21 = *(const short8*)(sWb2 + bb + 32);
    f32x4 acc = {0.f, 0.f, 0.f, 0.f};
    acc = __builtin_amdgcn_mfma_f32_16x16x32_bf16(as0, b10, acc, 0, 0, 0);
    acc = __builtin_amdgcn_mfma_f32_16x16x32_bf16(as1, b11, acc, 0, 0, 0);
    acc = __builtin_amdgcn_mfma_f32_16x16x32_bf16(am0, b20, acc, 0, 0, 0);
    acc = __builtin_amdgcn_mfma_f32_16x16x32_bf16(am1, b21, acc, 0, 0, 0);
    return acc;
}

// ---- k_pre: blocks 0-255 = dsd (R9-verified branch), 256+ = E_s->bf16 cvt.
// LDS (dsd): sXs[32x72] sXm[32x72] sW21b[64x72] sW22b[64x72] sS1[32x64 f]
//            = 35840 B.
__global__ __launch_bounds__(512, 6) void k_pre(
    const float* __restrict__ E_s, const float* __restrict__ E_d,
    const float* __restrict__ W21, const float* __restrict__ W22,
    const float* __restrict__ W11, const float* __restrict__ W12,
    const int* __restrict__ label, const int* __restrict__ dsd_1,
    const int* __restrict__ dsd_2,
    unsigned short* __restrict__ Ebf, float* __restrict__ emb_dise)
{
    __shared__ float4 smraw[2240];   // 35840 B
    const int tid = threadIdx.x;

    if (blockIdx.x >= 256) {
        // ---------------- cvt: 8 elems/thread ----------------
        int t = (blockIdx.x - 256) * 512 + tid;
        if (t >= 400008) return;
        const float4* p = reinterpret_cast<const float4*>(E_s) + (size_t)t * 2;
        float4 a = p[0], b = p[1];
        ushort8 o;
        o[0] = bf16bits(a.x); o[1] = bf16bits(a.y); o[2] = bf16bits(a.z); o[3] = bf16bits(a.w);
        o[4] = bf16bits(b.x); o[5] = bf16bits(b.y); o[6] = bf16bits(b.z); o[7] = bf16bits(b.w);
        *(reinterpret_cast<ushort8*>(Ebf) + t) = o;
        return;
    }

    // ---------------- dsd: 4 b per block, 8 waves ----------------
    const int lane = tid & 63, w = rfl(tid >> 6);
    const int m_ = lane & 15, quad = lane >> 4;
    const int b0 = blockIdx.x * 4;
    unsigned short* sXs   = (unsigned short*)smraw;   // 32x72
    unsigned short* sXm   = sXs + 2304;               // 32x72
    unsigned short* sW21b = sXm + 2304;               // 64x72 (W21 -> W11)
    unsigned short* sW22b = sW21b + 4608;             // 64x72 (W22 -> W12)
    float* sS1 = (float*)(sW22b + 4608);              // 32x64 fp32

    // Phase 0: W21/W22 -> bf16 LDS.
    {
        int row = tid >> 3, c0 = (tid & 7) << 3;
        const float* p1 = W21 + row * 64 + c0;
        const float* p2 = W22 + row * 64 + c0;
#pragma unroll
        for (int i = 0; i < 8; ++i) {
            sW21b[row * XP + c0 + i] = bf16bits(p1[i]);
            sW22b[row * XP + c0 + i] = bf16bits(p2[i]);
        }
    }

    // Phase 1: gathers + build stage-1 A rows (wave w: rows 4w..4w+3).
#pragma unroll
    for (int i = 0; i < 4; ++i) {
        int rl = w * 4 + i;
        int row = b0 * 8 + rl;
        int is = dsd_1[row];
        float es = E_s[(size_t)is * 64 + lane];
        const int* d2 = dsd_2 + row * 8;
        float sA = 0.f; int cnt = 0;
#pragma unroll
        for (int h = 0; h < 8; ++h) {
            int id = d2[h];
            cnt += (id != 0);
            sA += E_d[(size_t)id * 64 + lane];   // E_d[0] == 0
        }
        float wgt = cnt > 0 ? 1.f / ((float)cnt + 1e-8f) : 0.f;
        float A = sA * wgt;
        sXs[rl * XP + lane] = bf16bits(A + es);
        sXm[rl * XP + lane] = bf16bits(A * es);
    }
    __syncthreads();

    // Phase 2: stage-1 MFMA: wave w -> Mt=w>>2, J=w&3; all 16 rows valid.
    {
        const int Mt = w >> 2, J = w & 3;
        f32x4 acc = pair_mfma(sXs, sXm, sW21b, sW22b,
                              16 * Mt + m_, 16 * J + m_, quad);
#pragma unroll
        for (int r = 0; r < 4; ++r)
            sS1[(16 * Mt + quad * 4 + r) * 64 + J * 16 + m_] = leakyf(acc[r]);
    }
    __syncthreads();

    // Phase 3: waves 0-3 build stage-2 A rows; waves 4-7 convert W11/W12.
    if (w < 4) {
        int bb = b0 + w;
        float sE = 0.f; int cnt = 0;
        const int* d1 = dsd_1 + bb * 8;
#pragma unroll
        for (int h = 0; h < 8; ++h) {
            sE += sS1[(w * 8 + h) * 64 + lane];
            cnt += (d1[h] != 0);
        }
        float wgt = cnt > 0 ? 1.f / ((float)cnt + 1e-8f) : 0.f;
        float A3 = sE * wgt;
        float td = E_d[(size_t)label[bb] * 64 + lane];
        sXs[w * XP + lane] = bf16bits(A3 + td);
        sXm[w * XP + lane] = bf16bits(A3 * td);
    } else {
        int t2 = tid - 256;                 // 0..255
        int row = t2 >> 2, c0 = (t2 & 3) << 4;
        const float* p1 = W11 + row * 64 + c0;
        const float* p2 = W12 + row * 64 + c0;
#pragma unroll
        for (int i = 0; i < 16; ++i) {
            sW21b[row * XP + c0 + i] = bf16bits(p1[i]);
            sW22b[row * XP + c0 + i] = bf16bits(p2[i]);
        }
    }
    __syncthreads();

    // Phase 4: stage-2 MFMA (waves 0-3, J=w): rows 0-3 valid (quad 0).
    if (w < 4) {
        f32x4 acc = pair_mfma(sXs, sXm, sW21b, sW22b, m_, 16 * w + m_, quad);
        if (quad == 0) {
#pragma unroll
            for (int r = 0; r < 4; ++r)
                emb_dise[(size_t)(b0 + r) * 64 + w * 16 + m_] = leakyf(acc[r]);
        }
    }
}

// ---- k_main: usu only, one block per b, 8 waves (R9 structure).
// LDS: sXb[64x72] sW3b sW21b sW22b sW1ub [64x72 each] (ushort)
//      sA2[512] sES1[512] (float) = 50176 B -> 3 blocks/CU.
__global__ __launch_bounds__(512, 6) void k_main(
    const float* __restrict__ E_s, const unsigned short* __restrict__ Ebf,
    const float* __restrict__ W3, const float* __restrict__ W21u,
    const float* __restrict__ W22u, const float* __restrict__ W1u,
    const int* __restrict__ usu_1, const int* __restrict__ usu_2,
    const int* __restrict__ usu_3, float* __restrict__ emb_user)
{
    __shared__ float4 smraw[3136];   // 50176 B
    const int tid = threadIdx.x, lane = tid & 63, w = rfl(tid >> 6);
    const int m_ = lane & 15, quad = lane >> 4;
    const int b = blockIdx.x;

    unsigned short* sXb   = (unsigned short*)smraw;   // 64x72
    unsigned short* sW3b  = sXb + 4608;
    unsigned short* sW21b = sW3b + 4608;
    unsigned short* sW22b = sW21b + 4608;
    unsigned short* sW1ub = sW22b + 4608;
    float* sA2  = (float*)(sW1ub + 4608);             // 8x64
    float* sES1 = sA2 + 512;                          // 8x64
    unsigned short* sXs = sXb;                        // phase3 overlay: 16x72
    unsigned short* sXm = sXb + 16 * XP;

    const int sub = lane >> 4, cg = lane & 15;

    // Hoist indices: one coalesced load per row.
    int idv[8];
#pragma unroll
    for (int i = 0; i < 8; ++i)
        idv[i] = usu_3[((size_t)(b * 64 + w * 8 + i)) * 16 + cg];

    // Phase 0: W3/W21u/W22u/W1u -> bf16 LDS (8 elems/thread each).
    {
        int row = tid >> 3, c0 = (tid & 7) << 3;
        const float* p3 = W3 + row * 64 + c0;
        const float* p1 = W21u + row * 64 + c0;
        const float* p2 = W22u + row * 64 + c0;
        const float* pf = W1u + row * 64 + c0;
#pragma unroll
        for (int i = 0; i < 8; ++i) {
            sW3b[row * XP + c0 + i]  = bf16bits(p3[i]);
            sW21b[row * XP + c0 + i] = bf16bits(p1[i]);
            sW22b[row * XP + c0 + i] = bf16bits(p2[i]);
            sW1ub[row * XP + c0 + i] = bf16bits(pf[i]);
        }
    }

    // Phase 1: transposed gather + masked-avg (R8-verified); wave w rows 8w..8w+7.
#pragma unroll 2
    for (int i = 0; i < 8; ++i) {
        int ql = w * 8 + i;
        unsigned long long nzm = __ballot(idv[i] != 0) & 0xFFFFull;
        int cnt = (int)__popcll(nzm);
        float wgt = cnt > 0 ? 1.f / ((float)cnt + 1e-8f) : 0.f;
        float a0 = 0.f, a1 = 0.f, a2 = 0.f, a3 = 0.f;
#pragma unroll
        for (int k = 0; k < 4; ++k) {
            int id = __shfl(idv[i], k * 4 + sub, 64);
            uint2 v = *reinterpret_cast<const uint2*>(Ebf + (size_t)id * 64 + cg * 4);
            a0 += bflo(v.x); a1 += bfhi(v.x);    // Ebf row 0 == 0
            a2 += bflo(v.y); a3 += bfhi(v.y);
        }
        a0 += __shfl_xor(a0, 16, 64); a1 += __shfl_xor(a1, 16, 64);
        a2 += __shfl_xor(a2, 16, 64); a3 += __shfl_xor(a3, 16, 64);
        a0 += __shfl_xor(a0, 32, 64); a1 += __shfl_xor(a1, 32, 64);
        a2 += __shfl_xor(a2, 32, 64); a3 += __shfl_xor(a3, 32, 64);
        a0 *= wgt; a1 *= wgt; a2 *= wgt; a3 *= wgt;
        unsigned int q0 = ((unsigned int)bf16bits(a1) << 16) | bf16bits(a0);
        unsigned int q1 = ((unsigned int)bf16bits(a3) << 16) | bf16bits(a2);
        if (sub == 0) {
            uint2 st; st.x = q0; st.y = q1;
            *reinterpret_cast<uint2*>(sXb + ql * XP + cg * 4) = st;
        }
    }
    __syncthreads();

    // Phase 2: Y = leaky(X @ W3^T) via MFMA; u2-reduction in C-layout.
    {
        const int wt = w >> 1, J0 = (w & 1) * 2;
        const int base = (16 * wt + m_) * XP + quad * 8;
        short8 a0 = *(const short8*)(sXb + base);
        short8 a1 = *(const short8*)(sXb + base + 32);
        int cp0 = 0, cp1 = 0;
        const int* m2 = usu_2 + (b * 8 + 2 * wt) * 8;
#pragma unroll
        for (int u = 0; u < 8; ++u) { cp0 += (m2[u] != 0); cp1 += (m2[u + 8] != 0); }
        float wg0 = cp0 > 0 ? 1.f / ((float)cp0 + 1e-8f) : 0.f;
        float wg1 = cp1 > 0 ? 1.f / ((float)cp1 + 1e-8f) : 0.f;
#pragma unroll
        for (int jj = 0; jj < 2; ++jj) {
            int J = J0 + jj;
            const int wb = (16 * J + m_) * XP + quad * 8;
            short8 b0 = *(const short8*)(sW3b + wb);
            short8 b1 = *(const short8*)(sW3b + wb + 32);
            f32x4 acc = {0.f, 0.f, 0.f, 0.f};
            acc = __builtin_amdgcn_mfma_f32_16x16x32_bf16(a0, b0, acc, 0, 0, 0);
            acc = __builtin_amdgcn_mfma_f32_16x16x32_bf16(a1, b1, acc, 0, 0, 0);
            float t = leakyf(acc[0]) + leakyf(acc[1]) + leakyf(acc[2]) + leakyf(acc[3]);
            t += __shfl_xor(t, 16, 64);
            if (quad == 0) sA2[(2 * wt + 0) * 64 + J * 16 + m_] = t * wg0;
            if (quad == 2) sA2[(2 * wt + 1) * 64 + J * 16 + m_] = t * wg1;
        }
    }
    __syncthreads();

    // Phase 3a: build stage-2 A rows (wave w -> p=w): xs=x+u, xm=x*u.
    {
        float x = sA2[w * 64 + lane];
        float u1e = E_s[(size_t)usu_1[b * 8 + w] * 64 + lane];
        sXs[w * XP + lane] = bf16bits(x + u1e);
        sXm[w * XP + lane] = bf16bits(x * u1e);
    }
    __syncthreads();

    // Phase 3b: stage-2 MFMA (waves 0-3, J=w): rows 0-7 valid.
    if (w < 4) {
        f32x4 acc = pair_mfma(sXs, sXm, sW21b, sW22b, m_, 16 * w + m_, quad);
        if (quad < 2) {
#pragma unroll
            for (int r = 0; r < 4; ++r)
                sES1[(quad * 4 + r) * 64 + w * 16 + m_] = leakyf(acc[r]);
        }
    }
    __syncthreads();

    // Phase 3c: masked-avg of es1 rows -> bf16 into sXb row 0 (wave 0).
    if (w == 0) {
        float sE = 0.f; int cnt = 0;
        const int* u1i = usu_1 + b * 8;
#pragma unroll
        for (int h = 0; h < 8; ++h) {
            sE += sES1[h * 64 + lane];
            cnt += (u1i[h] != 0);
        }
        float wgt = cnt > 0 ? 1.f / ((float)cnt + 1e-8f) : 0.f;
        sXb[lane] = bf16bits(sE * wgt);
    }
    __syncthreads();

    // Phase 3d: final W1u MFMA (waves 0-3, J=w): only M-row 0 valid.
    if (w < 4) {
        const int fb = m_ * XP + quad * 8;
        short8 fa0 = *(const short8*)(sXb + fb);
        short8 fa1 = *(const short8*)(sXb + fb + 32);
        const int bb = (16 * w + m_) * XP + quad * 8;
        short8 fb0 = *(const short8*)(sW1ub + bb);
        short8 fb1 = *(const short8*)(sW1ub + bb + 32);
        f32x4 acc = {0.f, 0.f, 0.f, 0.f};
        acc = __builtin_amdgcn_mfma_f32_16x16x32_bf16(fa0, fb0, acc, 0, 0, 0);
        acc = __builtin_amdgcn_mfma_f32_16x16x32_bf16(fa1, fb1, acc, 0, 0, 0);
        if (quad == 0)
            emb_user[(size_t)b * 64 + w * 16 + m_] = leakyf(acc[0]);
    }
}

// ---- epilogue: out[b] = dot(emb_dise[b], emb_user[b]) ----
__global__ __launch_bounds__(256) void k_dot(const float* __restrict__ ed,
                                             const float* __restrict__ eu,
                                             float* __restrict__ out) {
    const int lane = threadIdx.x & 63;
    const int b = rfl((int)((blockIdx.x * blockDim.x + threadIdx.x) >> 6));
    float pr = ed[(size_t)b * 64 + lane] * eu[(size_t)b * 64 + lane];
#pragma unroll
    for (int off = 32; off > 0; off >>= 1) pr += __shfl_down(pr, off, 64);
    if (lane == 0) out[b] = pr;
}

extern "C" void kernel_launch(void* const* d_in, const int* in_sizes, int n_in,
                              void* d_out, int out_size, void* d_ws, size_t ws_size,
                              hipStream_t stream) {
    const float* E_s  = (const float*)d_in[0];
    const float* E_d  = (const float*)d_in[1];
    const float* W_dsd_21 = (const float*)d_in[2];
    const float* W_dsd_22 = (const float*)d_in[3];
    const float* W_dsd_11 = (const float*)d_in[4];
    const float* W_dsd_12 = (const float*)d_in[5];
    const float* W_usu_3  = (const float*)d_in[6];
    const float* W_usu_21 = (const float*)d_in[7];
    const float* W_usu_22 = (const float*)d_in[8];
    const float* W_usu_1  = (const float*)d_in[9];
    const int* label = (const int*)d_in[10];
    const int* dsd_1 = (const int*)d_in[11];
    const int* dsd_2 = (const int*)d_in[12];
    const int* usu_1 = (const int*)d_in[13];
    const int* usu_2 = (const int*)d_in[14];
    const int* usu_3 = (const int*)d_in[15];
    float* out = (float*)d_out;

    // ws: Ebf [50001*64 bf16 = 6,400,128 B] | emb_dise [256 KB] | emb_user [256 KB]
    unsigned short* Ebf = (unsigned short*)d_ws;
    float* emb_dise = (float*)((char*)d_ws + 6400128);
    float* emb_user = emb_dise + 1024 * 64;

    k_pre<<<1038, 512, 0, stream>>>(E_s, E_d, W_dsd_21, W_dsd_22, W_dsd_11, W_dsd_12,
                                    label, dsd_1, dsd_2, Ebf, emb_dise);
    k_main<<<1024, 512, 0, stream>>>(E_s, Ebf, W_usu_3, W_usu_21, W_usu_22, W_usu_1,
                                     usu_1, usu_2, usu_3, emb_user);
    k_dot<<<256, 256, 0, stream>>>(emb_dise, emb_user, out);
}

// Round 12
// 115.126 us; speedup vs baseline: 1.0450x; 1.0450x over previous
//
#include <hip/hip_runtime.h>
#include <hip/hip_bf16.h>

// HGNN forward, MI355X.
// R12 = exact revert to R9 (best measured: 116.1us, absmax 1.22e-4).
// R10 (wave-autonomous stage-1: +3.6us, MFMA duplication) and R11 (dsd
// moved to pre-kernel: +4.2us, lost intra-kernel dsd/usu overlap) both
// regressed; R9 is the measured optimum. Structure:
//  - k_cvt: E_s -> bf16 table (6.4MB; halves gather lines, R5).
//  - k_main: 1024 usu blocks (transposed gather R8 -> MFMA W3 R7 ->
//    MFMA pair stage-2 R9) + 256 dsd blocks (fp32 gather -> bf16 MFMA
//    stage-1/2 R9), co-resident for latency overlap.
//  - k_dot: final 64-dot.
// Remaining time is ~70% harness-fixed (268MB d_ws poison fill @6.1TB/s
// + input restores); kernel portion is gather-latency-bound.

typedef __attribute__((ext_vector_type(8))) short short8;
typedef __attribute__((ext_vector_type(8))) unsigned short ushort8;
typedef __attribute__((ext_vector_type(4))) float f32x4;

__device__ __forceinline__ int rfl(int v) { return __builtin_amdgcn_readfirstlane(v); }
__device__ __forceinline__ float bcastf(float v, int l) {
    return __int_as_float(__builtin_amdgcn_readlane(__float_as_int(v), l));
}
__device__ __forceinline__ float leakyf(float x) { return x >= 0.f ? x : 0.2f * x; }

__device__ __forceinline__ unsigned short bf16bits(float x) {
    __hip_bfloat16 h = __float2bfloat16(x);
    return __builtin_bit_cast(unsigned short, h);
}
__device__ __forceinline__ float bflo(unsigned int u) { return __uint_as_float(u << 16); }
__device__ __forceinline__ float bfhi(unsigned int u) { return __uint_as_float(u & 0xffff0000u); }

// Swizzled LDS fp32 weight layout (R3-verified): element [j][k] at float4
// index 16*j + (((k>>2)+j)&15). 512-thread stager: 2 float4 per thread.
__device__ __forceinline__ void stage_w512(float* dst, const float* __restrict__ W, int tid) {
#pragma unroll
    for (int c = 0; c < 2; ++c) {
        int f4 = c * 512 + tid;
        int j = f4 >> 4, g = f4 & 15;
        float4 v = reinterpret_cast<const float4*>(W)[f4];
        reinterpret_cast<float4*>(dst)[(j << 4) + ((g + j) & 15)] = v;
    }
}

__device__ __forceinline__ float dot1_lds(float x, const float* w, int lane) {
    float a0 = 0.f, a1 = 0.f, a2 = 0.f, a3 = 0.f;
#pragma unroll
    for (int g = 0; g < 16; ++g) {
        float4 c = reinterpret_cast<const float4*>(w)[(lane << 4) + ((g + lane) & 15)];
        int k = 4 * g;
        a0 = fmaf(bcastf(x, k + 0), c.x, a0);
        a1 = fmaf(bcastf(x, k + 1), c.y, a1);
        a2 = fmaf(bcastf(x, k + 2), c.z, a2);
        a3 = fmaf(bcastf(x, k + 3), c.w, a3);
    }
    return (a0 + a1) + (a2 + a3);
}

// ---- E_s fp32 -> bf16 table ----
__global__ __launch_bounds__(256) void k_cvt(const float* __restrict__ E_s,
                                             unsigned short* __restrict__ T) {
    int t = blockIdx.x * 256 + threadIdx.x;
    if (t >= 400008) return;
    const float4* p = reinterpret_cast<const float4*>(E_s) + (size_t)t * 2;
    float4 a = p[0], b = p[1];
    ushort8 o;
    o[0] = bf16bits(a.x); o[1] = bf16bits(a.y); o[2] = bf16bits(a.z); o[3] = bf16bits(a.w);
    o[4] = bf16bits(b.x); o[5] = bf16bits(b.y); o[6] = bf16bits(b.z); o[7] = bf16bits(b.w);
    *(reinterpret_cast<ushort8*>(T) + t) = o;
}

#define XP 72   // bf16 matrix row pitch in shorts (144 B: 16B-aligned)

// 4-MFMA pair-matmul accumulate: acc += As@Wb1(K32x2) + Am@Wb2(K32x2)
__device__ __forceinline__ f32x4 pair_mfma(
    const unsigned short* sXs, const unsigned short* sXm,
    const unsigned short* sWb1, const unsigned short* sWb2,
    int arow, int brow, int quad)
{
    const int ab = arow * XP + quad * 8;
    const int bb = brow * XP + quad * 8;
    short8 as0 = *(const short8*)(sXs + ab);
    short8 as1 = *(const short8*)(sXs + ab + 32);
    short8 am0 = *(const short8*)(sXm + ab);
    short8 am1 = *(const short8*)(sXm + ab + 32);
    short8 b10 = *(const short8*)(sWb1 + bb);
    short8 b11 = *(const short8*)(sWb1 + bb + 32);
    short8 b20 = *(const short8*)(sWb2 + bb);
    short8 b21 = *(const short8*)(sWb2 + bb + 32);
    f32x4 acc = {0.f, 0.f, 0.f, 0.f};
    acc = __builtin_amdgcn_mfma_f32_16x16x32_bf16(as0, b10, acc, 0, 0, 0);
    acc = __builtin_amdgcn_mfma_f32_16x16x32_bf16(as1, b11, acc, 0, 0, 0);
    acc = __builtin_amdgcn_mfma_f32_16x16x32_bf16(am0, b20, acc, 0, 0, 0);
    acc = __builtin_amdgcn_mfma_f32_16x16x32_bf16(am1, b21, acc, 0, 0, 0);
    return acc;
}

// LDS (usu): sXb[64x72] sW3b[64x72] sW21b[64x72] sW22b[64x72] (ushort)
//            sA2[512] sES1[512] (float) = 40960 B.
// LDS (dsd): sXs[32x72] sXm[32x72] sW21b[64x72] sW22b[64x72] sS1[32x64 f]
//            = 35840 B.
__global__ __launch_bounds__(512, 6) void k_main(
    const float* __restrict__ E_s, const unsigned short* __restrict__ Ebf,
    const float* __restrict__ E_d,
    const float* __restrict__ W21, const float* __restrict__ W22,
    const float* __restrict__ W11, const float* __restrict__ W12,
    const float* __restrict__ W3, const float* __restrict__ W21u,
    const float* __restrict__ W22u, const float* __restrict__ W1u,
    const int* __restrict__ label, const int* __restrict__ dsd_1,
    const int* __restrict__ dsd_2, const int* __restrict__ usu_1,
    const int* __restrict__ usu_2, const int* __restrict__ usu_3,
    float* __restrict__ emb_dise, float* __restrict__ emb_user)
{
    __shared__ float4 smraw[2560];   // 40960 B
    const int tid = threadIdx.x, lane = tid & 63, w = rfl(tid >> 6);
    const int m_ = lane & 15, quad = lane >> 4;

    if (blockIdx.x < 1024) {
        // ================= usu branch: one block per b, 8 waves =========
        const int b = blockIdx.x;
        unsigned short* sXb   = (unsigned short*)smraw;   // 64x72
        unsigned short* sW3b  = sXb + 4608;
        unsigned short* sW21b = sW3b + 4608;
        unsigned short* sW22b = sW21b + 4608;
        float* sA2  = (float*)(sW22b + 4608);             // 8x64
        float* sES1 = sA2 + 512;                          // 8x64
        unsigned short* sXs = sXb;                        // phase3: 16x72
        unsigned short* sXm = sXb + 16 * XP;

        const int sub = lane >> 4, cg = lane & 15;

        // Hoist indices: one coalesced load per row.
        int idv[8];
#pragma unroll
        for (int i = 0; i < 8; ++i)
            idv[i] = usu_3[((size_t)(b * 64 + w * 8 + i)) * 16 + cg];

        // Phase 0: W3/W21u/W22u -> bf16 LDS (8 elems/thread each).
        {
            int row = tid >> 3, c0 = (tid & 7) << 3;
            const float* p3 = W3 + row * 64 + c0;
            const float* p1 = W21u + row * 64 + c0;
            const float* p2 = W22u + row * 64 + c0;
#pragma unroll
            for (int i = 0; i < 8; ++i) {
                sW3b[row * XP + c0 + i]  = bf16bits(p3[i]);
                sW21b[row * XP + c0 + i] = bf16bits(p1[i]);
                sW22b[row * XP + c0 + i] = bf16bits(p2[i]);
            }
        }

        // Phase 1: transposed gather + masked-avg (R8-verified).
#pragma unroll 2
        for (int i = 0; i < 8; ++i) {
            int ql = w * 8 + i;
            unsigned long long nzm = __ballot(idv[i] != 0) & 0xFFFFull;
            int cnt = (int)__popcll(nzm);
            float wgt = cnt > 0 ? 1.f / ((float)cnt + 1e-8f) : 0.f;
            float a0 = 0.f, a1 = 0.f, a2 = 0.f, a3 = 0.f;
#pragma unroll
            for (int k = 0; k < 4; ++k) {
                int id = __shfl(idv[i], k * 4 + sub, 64);
                uint2 v = *reinterpret_cast<const uint2*>(Ebf + (size_t)id * 64 + cg * 4);
                a0 += bflo(v.x); a1 += bfhi(v.x);
                a2 += bflo(v.y); a3 += bfhi(v.y);
            }
            a0 += __shfl_xor(a0, 16, 64); a1 += __shfl_xor(a1, 16, 64);
            a2 += __shfl_xor(a2, 16, 64); a3 += __shfl_xor(a3, 16, 64);
            a0 += __shfl_xor(a0, 32, 64); a1 += __shfl_xor(a1, 32, 64);
            a2 += __shfl_xor(a2, 32, 64); a3 += __shfl_xor(a3, 32, 64);
            a0 *= wgt; a1 *= wgt; a2 *= wgt; a3 *= wgt;
            unsigned int p0 = ((unsigned int)bf16bits(a1) << 16) | bf16bits(a0);
            unsigned int p1 = ((unsigned int)bf16bits(a3) << 16) | bf16bits(a2);
            if (sub == 0) {
                uint2 st; st.x = p0; st.y = p1;
                *reinterpret_cast<uint2*>(sXb + ql * XP + cg * 4) = st;
            }
        }
        __syncthreads();

        // Phase 2: Y = leaky(X @ W3^T) via MFMA; u2-reduction in C-layout.
        {
            const int wt = w >> 1, J0 = (w & 1) * 2;
            const int base = (16 * wt + m_) * XP + quad * 8;
            short8 a0 = *(const short8*)(sXb + base);
            short8 a1 = *(const short8*)(sXb + base + 32);
            int cp0 = 0, cp1 = 0;
            const int* m2 = usu_2 + (b * 8 + 2 * wt) * 8;
#pragma unroll
            for (int u = 0; u < 8; ++u) { cp0 += (m2[u] != 0); cp1 += (m2[u + 8] != 0); }
            float wg0 = cp0 > 0 ? 1.f / ((float)cp0 + 1e-8f) : 0.f;
            float wg1 = cp1 > 0 ? 1.f / ((float)cp1 + 1e-8f) : 0.f;
#pragma unroll
            for (int jj = 0; jj < 2; ++jj) {
                int J = J0 + jj;
                const int wb = (16 * J + m_) * XP + quad * 8;
                short8 b0 = *(const short8*)(sW3b + wb);
                short8 b1 = *(const short8*)(sW3b + wb + 32);
                f32x4 acc = {0.f, 0.f, 0.f, 0.f};
                acc = __builtin_amdgcn_mfma_f32_16x16x32_bf16(a0, b0, acc, 0, 0, 0);
                acc = __builtin_amdgcn_mfma_f32_16x16x32_bf16(a1, b1, acc, 0, 0, 0);
                float t = leakyf(acc[0]) + leakyf(acc[1]) + leakyf(acc[2]) + leakyf(acc[3]);
                t += __shfl_xor(t, 16, 64);
                if (quad == 0) sA2[(2 * wt + 0) * 64 + J * 16 + m_] = t * wg0;
                if (quad == 2) sA2[(2 * wt + 1) * 64 + J * 16 + m_] = t * wg1;
            }
        }
        __syncthreads();

        // Phase 3a: build stage-2 A rows (wave w -> p=w): xs=x+u, xm=x*u.
        {
            int p = w;
            float x = sA2[p * 64 + lane];
            float u1e = E_s[(size_t)usu_1[b * 8 + p] * 64 + lane];
            sXs[p * XP + lane] = bf16bits(x + u1e);
            sXm[p * XP + lane] = bf16bits(x * u1e);
        }
        __syncthreads();

        // Phase 3b: stage-2 MFMA (waves 0-3, J=w): rows 0-7 valid.
        if (w < 4) {
            f32x4 acc = pair_mfma(sXs, sXm, sW21b, sW22b, m_, 16 * w + m_, quad);
            if (quad < 2) {
#pragma unroll
                for (int r = 0; r < 4; ++r)
                    sES1[(quad * 4 + r) * 64 + w * 16 + m_] = leakyf(acc[r]);
            }
        }
        __syncthreads();

        // Phase 3c: W1u fp32 swizzled over sW21b/sW22b region (dead now).
        stage_w512((float*)sW21b, W1u, tid);
        __syncthreads();

        // Phase 3d: final masked-avg + W1u transform (wave 0).
        if (w == 0) {
            float sE = 0.f; int cnt = 0;
            const int* u1i = usu_1 + b * 8;
#pragma unroll
            for (int h = 0; h < 8; ++h) {
                sE += sES1[h * 64 + lane];
                cnt += (u1i[h] != 0);
            }
            float wgt = cnt > 0 ? 1.f / ((float)cnt + 1e-8f) : 0.f;
            float eu = leakyf(dot1_lds(sE * wgt, (float*)sW21b, lane));
            emb_user[(size_t)b * 64 + lane] = eu;
        }
    } else {
        // ================= dsd branch: 4 b per block, 8 waves, MFMA ======
        const int b0 = (blockIdx.x - 1024) * 4;
        unsigned short* sXs   = (unsigned short*)smraw;   // 32x72
        unsigned short* sXm   = sXs + 2304;               // 32x72
        unsigned short* sW21b = sXm + 2304;               // 64x72 (W21 -> W11)
        unsigned short* sW22b = sW21b + 4608;             // 64x72 (W22 -> W12)
        float* sS1 = (float*)(sW22b + 4608);              // 32x64 fp32

        // Phase 0: W21/W22 -> bf16 LDS.
        {
            int row = tid >> 3, c0 = (tid & 7) << 3;
            const float* p1 = W21 + row * 64 + c0;
            const float* p2 = W22 + row * 64 + c0;
#pragma unroll
            for (int i = 0; i < 8; ++i) {
                sW21b[row * XP + c0 + i] = bf16bits(p1[i]);
                sW22b[row * XP + c0 + i] = bf16bits(p2[i]);
            }
        }

        // Phase 1: gathers + build stage-1 A rows (wave w: rows 4w..4w+3).
#pragma unroll
        for (int i = 0; i < 4; ++i) {
            int rl = w * 4 + i;
            int row = b0 * 8 + rl;
            int is = dsd_1[row];
            float es = E_s[(size_t)is * 64 + lane];
            const int* d2 = dsd_2 + row * 8;
            float sA = 0.f; int cnt = 0;
#pragma unroll
            for (int h = 0; h < 8; ++h) {
                int id = d2[h];
                cnt += (id != 0);
                sA += E_d[(size_t)id * 64 + lane];   // E_d[0] == 0
            }
            float wgt = cnt > 0 ? 1.f / ((float)cnt + 1e-8f) : 0.f;
            float A = sA * wgt;
            sXs[rl * XP + lane] = bf16bits(A + es);
            sXm[rl * XP + lane] = bf16bits(A * es);
        }
        __syncthreads();

        // Phase 2: stage-1 MFMA: wave w -> Mt=w>>2, J=w&3; all 16 rows valid.
        {
            const int Mt = w >> 2, J = w & 3;
            f32x4 acc = pair_mfma(sXs, sXm, sW21b, sW22b,
                                  16 * Mt + m_, 16 * J + m_, quad);
#pragma unroll
            for (int r = 0; r < 4; ++r)
                sS1[(16 * Mt + quad * 4 + r) * 64 + J * 16 + m_] = leakyf(acc[r]);
        }
        __syncthreads();

        // Phase 3: waves 0-3 build stage-2 A rows (p=w -> b0+w);
        //          waves 4-7 convert W11/W12 over W21/W22 slots.
        if (w < 4) {
            int bb = b0 + w;
            float sE = 0.f; int cnt = 0;
            const int* d1 = dsd_1 + bb * 8;
#pragma unroll
            for (int h = 0; h < 8; ++h) {
                sE += sS1[(w * 8 + h) * 64 + lane];
                cnt += (d1[h] != 0);
            }
            float wgt = cnt > 0 ? 1.f / ((float)cnt + 1e-8f) : 0.f;
            float A3 = sE * wgt;
            float td = E_d[(size_t)label[bb] * 64 + lane];
            sXs[w * XP + lane] = bf16bits(A3 + td);
            sXm[w * XP + lane] = bf16bits(A3 * td);
        } else {
            int t2 = tid - 256;                 // 0..255
            int row = t2 >> 2, c0 = (t2 & 3) << 4;
            const float* p1 = W11 + row * 64 + c0;
            const float* p2 = W12 + row * 64 + c0;
#pragma unroll
            for (int i = 0; i < 16; ++i) {
                sW21b[row * XP + c0 + i] = bf16bits(p1[i]);
                sW22b[row * XP + c0 + i] = bf16bits(p2[i]);
            }
        }
        __syncthreads();

        // Phase 4: stage-2 MFMA (waves 0-3, J=w): rows 0-3 valid (quad 0).
        if (w < 4) {
            f32x4 acc = pair_mfma(sXs, sXm, sW21b, sW22b, m_, 16 * w + m_, quad);
            if (quad == 0) {
#pragma unroll
                for (int r = 0; r < 4; ++r)
                    emb_dise[(size_t)(b0 + r) * 64 + w * 16 + m_] = leakyf(acc[r]);
            }
        }
    }
}

// ---- epilogue: out[b] = dot(emb_dise[b], emb_user[b]) ----
__global__ __launch_bounds__(256) void k_dot(const float* __restrict__ ed,
                                             const float* __restrict__ eu,
                                             float* __restrict__ out) {
    const int lane = threadIdx.x & 63;
    const int b = rfl((int)((blockIdx.x * blockDim.x + threadIdx.x) >> 6));
    float pr = ed[(size_t)b * 64 + lane] * eu[(size_t)b * 64 + lane];
#pragma unroll
    for (int off = 32; off > 0; off >>= 1) pr += __shfl_down(pr, off, 64);
    if (lane == 0) out[b] = pr;
}

extern "C" void kernel_launch(void* const* d_in, const int* in_sizes, int n_in,
                              void* d_out, int out_size, void* d_ws, size_t ws_size,
                              hipStream_t stream) {
    const float* E_s  = (const float*)d_in[0];
    const float* E_d  = (const float*)d_in[1];
    const float* W_dsd_21 = (const float*)d_in[2];
    const float* W_dsd_22 = (const float*)d_in[3];
    const float* W_dsd_11 = (const float*)d_in[4];
    const float* W_dsd_12 = (const float*)d_in[5];
    const float* W_usu_3  = (const float*)d_in[6];
    const float* W_usu_21 = (const float*)d_in[7];
    const float* W_usu_22 = (const float*)d_in[8];
    const float* W_usu_1  = (const float*)d_in[9];
    const int* label = (const int*)d_in[10];
    const int* dsd_1 = (const int*)d_in[11];
    const int* dsd_2 = (const int*)d_in[12];
    const int* usu_1 = (const int*)d_in[13];
    const int* usu_2 = (const int*)d_in[14];
    const int* usu_3 = (const int*)d_in[15];
    float* out = (float*)d_out;

    // ws: Ebf [50001*64 bf16 = 6,400,128 B] | emb_dise [256 KB] | emb_user [256 KB]
    unsigned short* Ebf = (unsigned short*)d_ws;
    float* emb_dise = (float*)((char*)d_ws + 6400128);
    float* emb_user = emb_dise + 1024 * 64;

    k_cvt<<<1563, 256, 0, stream>>>(E_s, Ebf);
    k_main<<<1280, 512, 0, stream>>>(E_s, Ebf, E_d,
                                     W_dsd_21, W_dsd_22, W_dsd_11, W_dsd_12,
                                     W_usu_3, W_usu_21, W_usu_22, W_usu_1,
                                     label, dsd_1, dsd_2, usu_1, usu_2, usu_3,
                                     emb_dise, emb_user);
    k_dot<<<256, 256, 0, stream>>>(emb_dise, emb_user, out);
}